// Round 5
// baseline (1960.478 us; speedup 1.0000x reference)
//
#include <hip/hip_runtime.h>

#define LOG2E 1.44269504088896340736f

typedef float f32x16 __attribute__((ext_vector_type(16)));
typedef float f32x8  __attribute__((ext_vector_type(8)));

__device__ __forceinline__ float fexp2(float x) { return __builtin_amdgcn_exp2f(x); }
__device__ __forceinline__ float frcp(float x)  { return __builtin_amdgcn_rcpf(x); }

__device__ __forceinline__ float sigmoid_f(float x) {
    return frcp(1.0f + fexp2(-x * LOG2E));
}
__device__ __forceinline__ float tanh_f(float x) {
    float t = fexp2(x * (2.0f * LOG2E));
    return (t - 1.0f) * frcp(t + 1.0f);
}

// Frontend-constant-index loop: vector element accesses become
// insert/extractelement on SSA values — no allocas, no scratch.
template <int I> struct IntC { static constexpr int value = I; };
template <int I, int N, typename F>
__device__ __forceinline__ void sfor(F&& f) {
    if constexpr (I < N) { f(IntC<I>{}); sfor<I + 1, N>(f); }
}

// One LSTM cell step over vectors. Weights are wave-uniform -> s_load +
// SGPR-operand v_fmac_f32.
template <int DIN, typename XVec>
__device__ __forceinline__ void lstm_cell_v(const float* __restrict__ Wih,   // 64 x DIN
                                            const float* __restrict__ Whh,   // 64 x 16
                                            const float* __restrict__ bih,   // 64
                                            const float* __restrict__ bhh,   // 64
                                            const XVec& x,
                                            const f32x16& hin,
                                            f32x16& c,
                                            f32x16& hout) {
    sfor<0, 16>([&](auto J) {
        constexpr int j = J.value;
        float gi = bih[j]      + bhh[j];
        float gf = bih[16 + j] + bhh[16 + j];
        float gg = bih[32 + j] + bhh[32 + j];
        float go = bih[48 + j] + bhh[48 + j];
        sfor<0, DIN>([&](auto K) {
            constexpr int k = K.value;
            gi += Wih[j * DIN + k]        * x[k];
            gf += Wih[(16 + j) * DIN + k] * x[k];
            gg += Wih[(32 + j) * DIN + k] * x[k];
            go += Wih[(48 + j) * DIN + k] * x[k];
        });
        sfor<0, 16>([&](auto K) {
            constexpr int k = K.value;
            gi += Whh[j * 16 + k]        * hin[k];
            gf += Whh[(16 + j) * 16 + k] * hin[k];
            gg += Whh[(32 + j) * 16 + k] * hin[k];
            go += Whh[(48 + j) * 16 + k] * hin[k];
        });
        float i_ = sigmoid_f(gi);
        float f_ = sigmoid_f(gf);
        float g_ = tanh_f(gg);
        float o_ = sigmoid_f(go);
        float cn = f_ * c[j] + i_ * g_;
        c[j]    = cn;
        hout[j] = o_ * tanh_f(cn);
    });
}

// waves_per_eu(2,2): min=max=2 pins the backend's occupancy target ->
// 256-VGPR planning budget, NO spill-to-reach-8-waves heuristic (round 4:
// min-only attr let the scheduler target 8 waves/EU = 64 VGPRs -> 2.6 GB
// of regalloc spill traffic). SSA vectors (round 4) keep allocas out of
// scratch/LDS (round 3: 64 KB LDS promote + 7.6M bank conflicts).
__global__
__attribute__((amdgpu_flat_work_group_size(256, 256)))
__attribute__((amdgpu_waves_per_eu(2, 2)))
void lstm_fused_kernel(const float* __restrict__ in,     // B x 8 x 8
                       const float* __restrict__ Wih0,   // 64 x 8
                       const float* __restrict__ Whh0,   // 64 x 16
                       const float* __restrict__ bih0,
                       const float* __restrict__ bhh0,
                       const float* __restrict__ Wih1,   // 64 x 16
                       const float* __restrict__ Whh1,   // 64 x 16
                       const float* __restrict__ bih1,
                       const float* __restrict__ bhh1,
                       const float* __restrict__ Wfc,    // 10 x 16
                       const float* __restrict__ bfc,    // 10
                       float* __restrict__ out,          // B x 10
                       int B) {
    int b = blockIdx.x * blockDim.x + threadIdx.x;
    if (b >= B) return;

    const float* xin = in + (size_t)b * 64;

    f32x16 h0 = {}, c0 = {}, h1 = {}, c1 = {};

    sfor<0, 8>([&](auto T) {
        constexpr int t = T.value;
        // 32B contiguous, 32B-aligned vector load (2x global_load_dwordx4,
        // constant offset folds into the instruction immediate).
        f32x8 xt = *(const f32x8*)(xin + t * 8);

        f32x16 nh0 = {};
        lstm_cell_v<8>(Wih0, Whh0, bih0, bhh0, xt, h0, c0, nh0);
        h0 = nh0;

        f32x16 nh1 = {};
        lstm_cell_v<16>(Wih1, Whh1, bih1, bhh1, h0, h1, c1, nh1);
        h1 = nh1;
    });

    // FC on last h1
    float* op = out + (size_t)b * 10;
    sfor<0, 10>([&](auto CI) {
        constexpr int ci = CI.value;
        float acc = bfc[ci];
        sfor<0, 16>([&](auto K) {
            constexpr int k = K.value;
            acc += Wfc[ci * 16 + k] * h1[k];
        });
        op[ci] = acc;
    });
}

extern "C" void kernel_launch(void* const* d_in, const int* in_sizes, int n_in,
                              void* d_out, int out_size, void* d_ws, size_t ws_size,
                              hipStream_t stream) {
    const float* in   = (const float*)d_in[0];
    const float* Wih0 = (const float*)d_in[1];
    const float* Whh0 = (const float*)d_in[2];
    const float* bih0 = (const float*)d_in[3];
    const float* bhh0 = (const float*)d_in[4];
    const float* Wih1 = (const float*)d_in[5];
    const float* Whh1 = (const float*)d_in[6];
    const float* bih1 = (const float*)d_in[7];
    const float* bhh1 = (const float*)d_in[8];
    const float* Wfc  = (const float*)d_in[9];
    const float* bfc  = (const float*)d_in[10];
    float* out = (float*)d_out;

    int B = in_sizes[0] / 64;   // 262144
    int block = 256;
    int grid = (B + block - 1) / block;
    lstm_fused_kernel<<<grid, block, 0, stream>>>(in, Wih0, Whh0, bih0, bhh0,
                                                  Wih1, Whh1, bih1, bhh1,
                                                  Wfc, bfc, out, B);
}

// Round 6
// 1776.447 us; speedup vs baseline: 1.1036x; 1.1036x over previous
//
#include <hip/hip_runtime.h>

#define LOG2E 1.44269504088896340736f

typedef float f32x16 __attribute__((ext_vector_type(16)));
typedef float f32x8  __attribute__((ext_vector_type(8)));

__device__ __forceinline__ float fexp2(float x) { return __builtin_amdgcn_exp2f(x); }
__device__ __forceinline__ float frcp(float x)  { return __builtin_amdgcn_rcpf(x); }

__device__ __forceinline__ float sigmoid_f(float x) {
    return frcp(1.0f + fexp2(-x * LOG2E));
}
__device__ __forceinline__ float tanh_f(float x) {
    float t = fexp2(x * (2.0f * LOG2E));
    return (t - 1.0f) * frcp(t + 1.0f);
}

// Frontend-constant-index loop: vector element accesses become
// insert/extractelement on SSA values — no allocas, no scratch.
template <int I> struct IntC { static constexpr int value = I; };
template <int I, int N, typename F>
__device__ __forceinline__ void sfor(F&& f) {
    if constexpr (I < N) { f(IntC<I>{}); sfor<I + 1, N>(f); }
}

// One LSTM cell step over vectors. Weights are wave-uniform -> s_load +
// SGPR-operand v_fmac_f32.
template <int DIN, typename XVec>
__device__ __forceinline__ void lstm_cell_v(const float* __restrict__ Wih,   // 64 x DIN
                                            const float* __restrict__ Whh,   // 64 x 16
                                            const float* __restrict__ bih,   // 64
                                            const float* __restrict__ bhh,   // 64
                                            const XVec& x,
                                            const f32x16& hin,
                                            f32x16& c,
                                            f32x16& hout) {
    sfor<0, 16>([&](auto J) {
        constexpr int j = J.value;
        float gi = bih[j]      + bhh[j];
        float gf = bih[16 + j] + bhh[16 + j];
        float gg = bih[32 + j] + bhh[32 + j];
        float go = bih[48 + j] + bhh[48 + j];
        sfor<0, DIN>([&](auto K) {
            constexpr int k = K.value;
            gi += Wih[j * DIN + k]        * x[k];
            gf += Wih[(16 + j) * DIN + k] * x[k];
            gg += Wih[(32 + j) * DIN + k] * x[k];
            go += Wih[(48 + j) * DIN + k] * x[k];
        });
        sfor<0, 16>([&](auto K) {
            constexpr int k = K.value;
            gi += Whh[j * 16 + k]        * hin[k];
            gf += Whh[(16 + j) * 16 + k] * hin[k];
            gg += Whh[(32 + j) * 16 + k] * hin[k];
            go += Whh[(48 + j) * 16 + k] * hin[k];
        });
        float i_ = sigmoid_f(gi);
        float f_ = sigmoid_f(gf);
        float g_ = tanh_f(gg);
        float o_ = sigmoid_f(go);
        float cn = f_ * c[j] + i_ * g_;
        c[j]    = cn;
        hout[j] = o_ * tanh_f(cn);
    });
}

// Empirical budget rule on this backend: granted VGPRs ≈ 256 / min_waves_per_eu
// (r4: (4)->64, r3/r5: (2,2)->124..128, both spilled). (1,1) -> full 256-VGPR
// budget; peak live pressure ~170-220 fits, zero spill. Runtime occupancy
// then comes from the ACTUAL VGPR count vs the 512-reg HW pool -> still
// 2 waves/SIMD resident.
__global__
__attribute__((amdgpu_flat_work_group_size(256, 256)))
__attribute__((amdgpu_waves_per_eu(1, 1)))
void lstm_fused_kernel(const float* __restrict__ in,     // B x 8 x 8
                       const float* __restrict__ Wih0,   // 64 x 8
                       const float* __restrict__ Whh0,   // 64 x 16
                       const float* __restrict__ bih0,
                       const float* __restrict__ bhh0,
                       const float* __restrict__ Wih1,   // 64 x 16
                       const float* __restrict__ Whh1,   // 64 x 16
                       const float* __restrict__ bih1,
                       const float* __restrict__ bhh1,
                       const float* __restrict__ Wfc,    // 10 x 16
                       const float* __restrict__ bfc,    // 10
                       float* __restrict__ out,          // B x 10
                       int B) {
    int b = blockIdx.x * blockDim.x + threadIdx.x;
    if (b >= B) return;

    const float* xin = in + (size_t)b * 64;

    f32x16 h0 = {}, c0 = {}, h1 = {}, c1 = {};

    sfor<0, 8>([&](auto T) {
        constexpr int t = T.value;
        // 32B contiguous, 32B-aligned vector load; offset folds into the
        // instruction immediate. Lines re-hit L1 across timesteps.
        f32x8 xt = *(const f32x8*)(xin + t * 8);

        f32x16 nh0 = {};
        lstm_cell_v<8>(Wih0, Whh0, bih0, bhh0, xt, h0, c0, nh0);
        h0 = nh0;

        f32x16 nh1 = {};
        lstm_cell_v<16>(Wih1, Whh1, bih1, bhh1, h0, h1, c1, nh1);
        h1 = nh1;
    });

    // FC on last h1
    float* op = out + (size_t)b * 10;
    sfor<0, 10>([&](auto CI) {
        constexpr int ci = CI.value;
        float acc = bfc[ci];
        sfor<0, 16>([&](auto K) {
            constexpr int k = K.value;
            acc += Wfc[ci * 16 + k] * h1[k];
        });
        op[ci] = acc;
    });
}

extern "C" void kernel_launch(void* const* d_in, const int* in_sizes, int n_in,
                              void* d_out, int out_size, void* d_ws, size_t ws_size,
                              hipStream_t stream) {
    const float* in   = (const float*)d_in[0];
    const float* Wih0 = (const float*)d_in[1];
    const float* Whh0 = (const float*)d_in[2];
    const float* bih0 = (const float*)d_in[3];
    const float* bhh0 = (const float*)d_in[4];
    const float* Wih1 = (const float*)d_in[5];
    const float* Whh1 = (const float*)d_in[6];
    const float* bih1 = (const float*)d_in[7];
    const float* bhh1 = (const float*)d_in[8];
    const float* Wfc  = (const float*)d_in[9];
    const float* bfc  = (const float*)d_in[10];
    float* out = (float*)d_out;

    int B = in_sizes[0] / 64;   // 262144
    int block = 256;
    int grid = (B + block - 1) / block;
    lstm_fused_kernel<<<grid, block, 0, stream>>>(in, Wih0, Whh0, bih0, bhh0,
                                                  Wih1, Whh1, bih1, bhh1,
                                                  Wfc, bfc, out, B);
}

// Round 7
// 456.274 us; speedup vs baseline: 4.2967x; 3.8934x over previous
//
#include <hip/hip_runtime.h>

#define LOG2E 1.44269504088896340736f

typedef float f32x16 __attribute__((ext_vector_type(16)));
typedef float f32x8  __attribute__((ext_vector_type(8)));

__device__ __forceinline__ float fexp2(float x) { return __builtin_amdgcn_exp2f(x); }
__device__ __forceinline__ float frcp(float x)  { return __builtin_amdgcn_rcpf(x); }

__device__ __forceinline__ float sigmoid_f(float x) {
    return frcp(1.0f + fexp2(-x * LOG2E));
}
__device__ __forceinline__ float tanh_f(float x) {
    float t = fexp2(x * (2.0f * LOG2E));
    return (t - 1.0f) * frcp(t + 1.0f);
}

// Frontend-constant-index loop: SSA vectors, no allocas.
template <int I> struct IntC { static constexpr int value = I; };
template <int I, int N, typename F>
__device__ __forceinline__ void sfor(F&& f) {
    if constexpr (I < N) { f(IntC<I>{}); sfor<I + 1, N>(f); }
}

// Broadcast one lane's float to the whole wave (result is wave-uniform ->
// lives in an SGPR; FMA consumes it as the single allowed scalar operand).
__device__ __forceinline__ float rdlane(float v, int lane_const) {
    return __int_as_float(__builtin_amdgcn_readlane(__float_as_int(v), lane_const));
}

// Layout: one WAVE per sample, one LANE per gate-row.
//   lane l = g*16 + j  (g: 0=i, 1=f, 2=g, 3=o — matches jnp.split order)
// Lane keeps row l of Wih/Whh for both layers in VGPRs, loaded ONCE
// (round-6 diagnosis: per-use weight re-streaming = 1.1M cyc/wave of
// exposed s_load latency). h is re-broadcast each step via v_readlane.
__global__
__attribute__((amdgpu_flat_work_group_size(256, 256)))
__attribute__((amdgpu_waves_per_eu(2, 8)))   // budget 128 >= ~115 live: no spill; 4 waves/SIMD
void lstm_lane_kernel(const float* __restrict__ in,     // B x 8 x 8
                      const float* __restrict__ Wih0,   // 64 x 8
                      const float* __restrict__ Whh0,   // 64 x 16
                      const float* __restrict__ bih0,
                      const float* __restrict__ bhh0,
                      const float* __restrict__ Wih1,   // 64 x 16
                      const float* __restrict__ Whh1,   // 64 x 16
                      const float* __restrict__ bih1,
                      const float* __restrict__ bhh1,
                      const float* __restrict__ Wfc,    // 10 x 16
                      const float* __restrict__ bfc,    // 10
                      float* __restrict__ out,          // B x 10
                      int B) {
    const int lane = threadIdx.x & 63;
    int bs = blockIdx.x * (blockDim.x >> 6) + (threadIdx.x >> 6);
    bs = __builtin_amdgcn_readfirstlane(bs);
    if (bs >= B) return;   // wave-uniform guard (grid is exact anyway)

    // ---- per-lane weight rows, resident for the whole kernel ----
    const f32x8  wih0 = *(const f32x8 *)(Wih0 + lane * 8);   // coalesced: 2KB/wave
    const f32x16 whh0 = *(const f32x16*)(Whh0 + lane * 16);
    const f32x16 wih1 = *(const f32x16*)(Wih1 + lane * 16);
    const f32x16 whh1 = *(const f32x16*)(Whh1 + lane * 16);
    const float  bb0  = bih0[lane] + bhh0[lane];
    const float  bb1  = bih1[lane] + bhh1[lane];

    const int jj   = lane & 15;
    const int srcF = jj + 16, srcG = jj + 32, srcO = jj + 48;
    const bool isG = ((lane >> 4) == 2);

    f32x16 h0s = {};   // wave-uniform h (SGPR-resident via readlane)
    f32x16 h1s = {};
    float  c0 = 0.f, c1 = 0.f;   // valid on lanes 0..15 (lane jj owns c[jj])

    const float* xin = in + (size_t)bs * 64;

    sfor<0, 8>([&](auto T) {
        constexpr int t = T.value;
        // x_t: wave-uniform address -> one broadcast line fetch
        const f32x8 xt = *(const f32x8*)(xin + t * 8);

        // ---------- layer 0: gate row `lane` ----------
        float a0 = bb0, a1 = 0.f;   // 2 chains for ILP
        sfor<0, 4>([&](auto K) { constexpr int k = K.value;
            a0 += wih0[2 * k]     * xt[2 * k];
            a1 += wih0[2 * k + 1] * xt[2 * k + 1];
        });
        sfor<0, 8>([&](auto K) { constexpr int k = K.value;
            a0 += whh0[2 * k]     * h0s[2 * k];
            a1 += whh0[2 * k + 1] * h0s[2 * k + 1];
        });
        const float acc = a0 + a1;
        const float sg  = sigmoid_f(acc);
        const float th  = tanh_f(acc);
        const float act = isG ? th : sg;          // v_cndmask, no divergence

        const float f_ = __shfl(act, srcF);
        const float g_ = __shfl(act, srcG);
        const float o_ = __shfl(act, srcO);
        c0 = f_ * c0 + act * g_;                  // act == i_j on lanes 0..15
        const float hv = o_ * tanh_f(c0);         // valid on lanes 0..15
        sfor<0, 16>([&](auto K) { constexpr int k = K.value;
            h0s[k] = rdlane(hv, k);
        });

        // ---------- layer 1 ----------
        float d0 = bb1, d1 = 0.f;
        sfor<0, 8>([&](auto K) { constexpr int k = K.value;
            d0 += wih1[2 * k]     * h0s[2 * k];
            d1 += wih1[2 * k + 1] * h0s[2 * k + 1];
        });
        sfor<0, 8>([&](auto K) { constexpr int k = K.value;
            d0 += whh1[2 * k]     * h1s[2 * k];
            d1 += whh1[2 * k + 1] * h1s[2 * k + 1];
        });
        const float accd = d0 + d1;
        const float sgd  = sigmoid_f(accd);
        const float thd  = tanh_f(accd);
        const float actd = isG ? thd : sgd;

        const float f1 = __shfl(actd, srcF);
        const float g1 = __shfl(actd, srcG);
        const float o1 = __shfl(actd, srcO);
        c1 = f1 * c1 + actd * g1;
        const float hv1 = o1 * tanh_f(c1);
        sfor<0, 16>([&](auto K) { constexpr int k = K.value;
            h1s[k] = rdlane(hv1, k);
        });
    });

    // ---- FC: lanes 0..9 each produce one output; 40B contiguous/wave ----
    if (lane < 10) {
        const float* wr = Wfc + lane * 16;        // 640B total, cache-resident
        float acc = bfc[lane];
        sfor<0, 16>([&](auto K) { constexpr int k = K.value;
            acc += wr[k] * h1s[k];
        });
        out[(size_t)bs * 10 + lane] = acc;
    }
}

extern "C" void kernel_launch(void* const* d_in, const int* in_sizes, int n_in,
                              void* d_out, int out_size, void* d_ws, size_t ws_size,
                              hipStream_t stream) {
    const float* in   = (const float*)d_in[0];
    const float* Wih0 = (const float*)d_in[1];
    const float* Whh0 = (const float*)d_in[2];
    const float* bih0 = (const float*)d_in[3];
    const float* bhh0 = (const float*)d_in[4];
    const float* Wih1 = (const float*)d_in[5];
    const float* Whh1 = (const float*)d_in[6];
    const float* bih1 = (const float*)d_in[7];
    const float* bhh1 = (const float*)d_in[8];
    const float* Wfc  = (const float*)d_in[9];
    const float* bfc  = (const float*)d_in[10];
    float* out = (float*)d_out;

    int B = in_sizes[0] / 64;                 // 262144 samples
    int wavesPerBlock = 4;                    // block = 256 threads
    int grid = (B + wavesPerBlock - 1) / wavesPerBlock;   // 65536 blocks
    lstm_lane_kernel<<<grid, 256, 0, stream>>>(in, Wih0, Whh0, bih0, bhh0,
                                               Wih1, Whh1, bih1, bhh1,
                                               Wfc, bfc, out, B);
}

// Round 8
// 149.248 us; speedup vs baseline: 13.1357x; 3.0572x over previous
//
#include <hip/hip_runtime.h>

#define LOG2E 1.44269504088896340736f

typedef short bf16x8 __attribute__((ext_vector_type(8)));
typedef float f32x4  __attribute__((ext_vector_type(4)));

template <int I> struct IntC { static constexpr int value = I; };
template <int I, int N, typename F>
__device__ __forceinline__ void sfor(F&& f) {
    if constexpr (I < N) { f(IntC<I>{}); sfor<I + 1, N>(f); }
}

__device__ __forceinline__ float fexp2(float x){ return __builtin_amdgcn_exp2f(x); }
__device__ __forceinline__ float frcp(float x){ return __builtin_amdgcn_rcpf(x); }
__device__ __forceinline__ float sigmoid_f(float x){ return frcp(1.f + fexp2(-x*LOG2E)); }
__device__ __forceinline__ float tanh_f(float x){ float t = fexp2(x*(2.f*LOG2E)); return (t-1.f)*frcp(t+1.f); }

// bf16 split helpers: hi = truncated top-16 bits (exact f32), lo = remainder.
__device__ __forceinline__ float hi_part(float x){
    return __uint_as_float(__float_as_uint(x) & 0xFFFF0000u);
}
__device__ __forceinline__ unsigned pk2(float a, float b){   // (lo16=a, hi16=b) bf16-trunc
    return (__float_as_uint(a)>>16) | (__float_as_uint(b)&0xFFFF0000u);
}
__device__ __forceinline__ unsigned pk2lo(float a, float b){ // packed residuals
    return pk2(a - hi_part(a), b - hi_part(b));
}

// Per-wave LDS regions (byte offsets). Strides chosen for 16B alignment and
// <=2-way bank aliasing (free, m136): x rows 144B, h rows 48B.
#define XH   0        // x hi : 16 samples * 144B  (s*144 + t*16)
#define XL   2304     // x lo
#define H0H  4608     // h0 hi: 16 samples * 48B   (s*48, 32B used)
#define H0L  5376
#define H1H  6144
#define H1L  6912
#define ZRO  7680     // 32B of zeros (K-pad reads)
#define WSTRIDE 7712

#define MFMA16 __builtin_amdgcn_mfma_f32_16x16x32_bf16

// One wave = 16 samples. MFMA A = weights (m=gate row), B = [x;h] (n=sample).
// Assumed A/B frag layout (std CDNA): A: row=l&15, k=8*(l>>4)+e; B: col=l&15,
// k=8*(l>>4)+e. C/D verified (m89): col=l&15, row=4*(l>>4)+reg.
__global__
__attribute__((amdgpu_flat_work_group_size(256,256)))
__attribute__((amdgpu_waves_per_eu(1,4)))
void lstm_mfma_kernel(const float* __restrict__ in,
                      const float* __restrict__ Wih0, const float* __restrict__ Whh0,
                      const float* __restrict__ bih0, const float* __restrict__ bhh0,
                      const float* __restrict__ Wih1, const float* __restrict__ Whh1,
                      const float* __restrict__ bih1, const float* __restrict__ bhh1,
                      const float* __restrict__ Wfc,  const float* __restrict__ bfc,
                      float* __restrict__ out, int B)
{
    __shared__ __align__(16) char smem[WSTRIDE*4];
    const int lane = threadIdx.x & 63;
    const int wid  = threadIdx.x >> 6;
    char* W = smem + wid*WSTRIDE;
    const int q  = lane >> 4;       // k-group / row-group
    const int sl = lane & 15;       // sample slot (MFMA col)
    const long s0 = (long)(blockIdx.x*4 + wid)*16;

    // ---- zero h sheets + zero-pad region (3104B starting at H0H) ----
    {
        uint4 z{0,0,0,0};
        sfor<0,4>([&](auto I){ int off = lane*16 + I.value*1024;
            if (off < 3104) *(uint4*)(W + H0H + off) = z; });
    }

    // ---- stage x: split bf16 hi/lo, packed pairs. Coalesced: wave reads
    // 4KB contiguous (16 samples * 256B). Lane covers 16 consecutive floats.
    {
        const float* xp = in + (s0 + (lane>>2))*64 + (lane&3)*16;
        float4 v0 = *(const float4*)(xp);
        float4 v1 = *(const float4*)(xp+4);
        float4 v2 = *(const float4*)(xp+8);
        float4 v3 = *(const float4*)(xp+12);
        char* xw = W + XH + (lane>>2)*144 + (lane&3)*32;
        *(uint4*)(xw)      = uint4{pk2(v0.x,v0.y), pk2(v0.z,v0.w), pk2(v1.x,v1.y), pk2(v1.z,v1.w)};
        *(uint4*)(xw+16)   = uint4{pk2(v2.x,v2.y), pk2(v2.z,v2.w), pk2(v3.x,v3.y), pk2(v3.z,v3.w)};
        char* xlw = W + XL + (lane>>2)*144 + (lane&3)*32;
        *(uint4*)(xlw)     = uint4{pk2lo(v0.x,v0.y), pk2lo(v0.z,v0.w), pk2lo(v1.x,v1.y), pk2lo(v1.z,v1.w)};
        *(uint4*)(xlw+16)  = uint4{pk2lo(v2.x,v2.y), pk2lo(v2.z,v2.w), pk2lo(v3.x,v3.y), pk2lo(v3.z,v3.w)};
    }

    // ---- weight A-frags (resident in VGPRs, hi/lo split) ----
    // layer0 virtual A (64 x K=32): k<8 -> Wih0, k<24 -> Whh0, else 0
    // layer1 virtual A (64 x 32):   k<16 -> Wih1, else Whh1
    bf16x8 a0h[4], a0l[4], a1h[4], a1l[4], afh, afl;
    f32x4 bias0[4], bias1[4], biasf;
    sfor<0,4>([&](auto MT){ constexpr int mt = MT.value;
        const int g = 16*mt + sl;
        sfor<0,8>([&](auto E){ constexpr int e = E.value;
            const int k = 8*q + e;
            float w0 = (k<8) ? Wih0[g*8+k] : (k<24 ? Whh0[g*16+(k-8)] : 0.f);
            a0h[mt][e] = (short)(__float_as_uint(w0)>>16);
            a0l[mt][e] = (short)(__float_as_uint(w0 - hi_part(w0))>>16);
            float w1 = (k<16) ? Wih1[g*16+k] : Whh1[g*16+(k-16)];
            a1h[mt][e] = (short)(__float_as_uint(w1)>>16);
            a1l[mt][e] = (short)(__float_as_uint(w1 - hi_part(w1))>>16);
        });
        sfor<0,4>([&](auto R){ constexpr int r = R.value;
            const int gb = 16*mt + 4*q + r;
            bias0[mt][r] = bih0[gb] + bhh0[gb];
            bias1[mt][r] = bih1[gb] + bhh1[gb];
        });
    });
    sfor<0,8>([&](auto E){ constexpr int e = E.value;
        const int k = 8*q + e;
        float wf = (sl<10 && k<16) ? Wfc[sl*16+k] : 0.f;
        afh[e] = (short)(__float_as_uint(wf)>>16);
        afl[e] = (short)(__float_as_uint(wf - hi_part(wf))>>16);
    });
    sfor<0,4>([&](auto R){ constexpr int r = R.value;
        const int gb = 4*q + r;
        biasf[r] = (gb<10) ? bfc[gb] : 0.f;
    });

    // ---- per-lane B-source addresses ----
    // layer0 B k-groups: q0=x_t[0..7], q1=h0[0..7], q2=h0[8..15], q3=0
    int l0hi, l0lo, xstep = 0;
    if (q==0)      { l0hi = XH  + sl*144; l0lo = XL  + sl*144; xstep = 16; }
    else if (q==1) { l0hi = H0H + sl*48;      l0lo = H0L + sl*48; }
    else if (q==2) { l0hi = H0H + sl*48 + 16; l0lo = H0L + sl*48 + 16; }
    else           { l0hi = ZRO; l0lo = ZRO; }
    // layer1 B: q0=h0[0..7], q1=h0[8..15], q2=h1[0..7], q3=h1[8..15]
    const int l1hi = (q==0)?H0H+sl*48 : (q==1)?H0H+sl*48+16 : (q==2)?H1H+sl*48 : H1H+sl*48+16;
    const int l1lo = (q==0)?H0L+sl*48 : (q==1)?H0L+sl*48+16 : (q==2)?H1L+sl*48 : H1L+sl*48+16;

    f32x4 c0{0,0,0,0}, c1{0,0,0,0};

    sfor<0,8>([&](auto T){ constexpr int t = T.value;
        // ================= layer 0 =================
        {
            bf16x8 Bh = *(const bf16x8*)(W + l0hi + t*xstep);
            bf16x8 Bl = *(const bf16x8*)(W + l0lo + t*xstep);
            f32x4 dd[4];
            sfor<0,4>([&](auto MT){ constexpr int mt = MT.value;
                f32x4 d = MFMA16(a0l[mt], Bh, bias0[mt], 0,0,0);
                d = MFMA16(a0h[mt], Bl, d, 0,0,0);
                d = MFMA16(a0h[mt], Bh, d, 0,0,0);
                dd[mt] = d;
            });
            f32x4 hv;
            sfor<0,4>([&](auto R){ constexpr int r = R.value;
                float iv = sigmoid_f(dd[0][r]);
                float fv = sigmoid_f(dd[1][r]);
                float gv = tanh_f   (dd[2][r]);
                float ov = sigmoid_f(dd[3][r]);
                float cn = fv*c0[r] + iv*gv;
                c0[r] = cn;
                hv[r] = ov * tanh_f(cn);
            });
            *(uint2*)(W + H0H + sl*48 + q*8) = uint2{pk2(hv[0],hv[1]),   pk2(hv[2],hv[3])};
            *(uint2*)(W + H0L + sl*48 + q*8) = uint2{pk2lo(hv[0],hv[1]), pk2lo(hv[2],hv[3])};
        }
        // ================= layer 1 =================
        {
            bf16x8 Bh = *(const bf16x8*)(W + l1hi);
            bf16x8 Bl = *(const bf16x8*)(W + l1lo);
            f32x4 dd[4];
            sfor<0,4>([&](auto MT){ constexpr int mt = MT.value;
                f32x4 d = MFMA16(a1l[mt], Bh, bias1[mt], 0,0,0);
                d = MFMA16(a1h[mt], Bl, d, 0,0,0);
                d = MFMA16(a1h[mt], Bh, d, 0,0,0);
                dd[mt] = d;
            });
            f32x4 hv;
            sfor<0,4>([&](auto R){ constexpr int r = R.value;
                float iv = sigmoid_f(dd[0][r]);
                float fv = sigmoid_f(dd[1][r]);
                float gv = tanh_f   (dd[2][r]);
                float ov = sigmoid_f(dd[3][r]);
                float cn = fv*c1[r] + iv*gv;
                c1[r] = cn;
                hv[r] = ov * tanh_f(cn);
            });
            *(uint2*)(W + H1H + sl*48 + q*8) = uint2{pk2(hv[0],hv[1]),   pk2(hv[2],hv[3])};
            *(uint2*)(W + H1L + sl*48 + q*8) = uint2{pk2lo(hv[0],hv[1]), pk2lo(hv[2],hv[3])};
        }
    });

    // ================= FC =================
    {
        const int fhi = (q==0)?H1H+sl*48 : (q==1)?H1H+sl*48+16 : ZRO;
        const int flo = (q==0)?H1L+sl*48 : (q==1)?H1L+sl*48+16 : ZRO;
        bf16x8 Bh = *(const bf16x8*)(W + fhi);
        bf16x8 Bl = *(const bf16x8*)(W + flo);
        f32x4 d = MFMA16(afl, Bh, biasf, 0,0,0);
        d = MFMA16(afh, Bl, d, 0,0,0);
        d = MFMA16(afh, Bh, d, 0,0,0);
        float* orow = out + (s0 + sl)*10;
        if (q==0)      { *(float2*)(orow)   = float2{d[0],d[1]}; *(float2*)(orow+2) = float2{d[2],d[3]}; }
        else if (q==1) { *(float2*)(orow+4) = float2{d[0],d[1]}; *(float2*)(orow+6) = float2{d[2],d[3]}; }
        else if (q==2) { *(float2*)(orow+8) = float2{d[0],d[1]}; }
    }
}

extern "C" void kernel_launch(void* const* d_in, const int* in_sizes, int n_in,
                              void* d_out, int out_size, void* d_ws, size_t ws_size,
                              hipStream_t stream) {
    const float* in   = (const float*)d_in[0];
    const float* Wih0 = (const float*)d_in[1];
    const float* Whh0 = (const float*)d_in[2];
    const float* bih0 = (const float*)d_in[3];
    const float* bhh0 = (const float*)d_in[4];
    const float* Wih1 = (const float*)d_in[5];
    const float* Whh1 = (const float*)d_in[6];
    const float* bih1 = (const float*)d_in[7];
    const float* bhh1 = (const float*)d_in[8];
    const float* Wfc  = (const float*)d_in[9];
    const float* bfc  = (const float*)d_in[10];
    float* out = (float*)d_out;

    int B = in_sizes[0] / 64;           // 262144 samples
    int grid = B / 64;                  // 16 samples/wave * 4 waves/block
    lstm_mfma_kernel<<<grid, 256, 0, stream>>>(in, Wih0, Whh0, bih0, bhh0,
                                               Wih1, Whh1, bih1, bhh1,
                                               Wfc, bfc, out, B);
}

// Round 9
// 142.455 us; speedup vs baseline: 13.7621x; 1.0477x over previous
//
#include <hip/hip_runtime.h>

#define LOG2E 1.44269504088896340736f

typedef short bf16x8 __attribute__((ext_vector_type(8)));
typedef float f32x4  __attribute__((ext_vector_type(4)));

template <int I> struct IntC { static constexpr int value = I; };
template <int I, int N, typename F>
__device__ __forceinline__ void sfor(F&& f) {
    if constexpr (I < N) { f(IntC<I>{}); sfor<I + 1, N>(f); }
}

__device__ __forceinline__ float fexp2(float x){ return __builtin_amdgcn_exp2f(x); }
__device__ __forceinline__ float frcp(float x){ return __builtin_amdgcn_rcpf(x); }
__device__ __forceinline__ float sigmoid_f(float x){ return frcp(1.f + fexp2(-x*LOG2E)); }
__device__ __forceinline__ float tanh_f(float x){ float t = fexp2(x*(2.f*LOG2E)); return (t-1.f)*frcp(t+1.f); }

__device__ __forceinline__ float hi_part(float x){
    return __uint_as_float(__float_as_uint(x) & 0xFFFF0000u);
}
__device__ __forceinline__ unsigned pk2(float a, float b){   // low16=bf16(a), high16=bf16(b)
    return (__float_as_uint(a)>>16) | (__float_as_uint(b)&0xFFFF0000u);
}
__device__ __forceinline__ unsigned pk2lo(float a, float b){ // packed residuals
    return pk2(a - hi_part(a), b - hi_part(b));
}
__device__ __forceinline__ bf16x8 mkB(unsigned d0,unsigned d1,unsigned d2,unsigned d3){
    uint4 u{d0,d1,d2,d3};
    return __builtin_bit_cast(bf16x8, u);
}

#define MFMA16 __builtin_amdgcn_mfma_f32_16x16x32_bf16

// One wave = 16 samples, ZERO LDS. Virtual-K permutation chosen so every
// lane's B-fragment is its OWN packed h registers (lane (q,sl) owns C/D rows
// 4q..4q+3 = units 4q..4q+3 of sample sl; B element k=8q+e is chosen to BE
// those units). A-fragments are loaded with the matching permutation.
//   layer0 K: e<4 -> h0[4q+e];  e>=4: q==0 -> x[e-4], q==1 -> x[e], else 0
//   layer1 K: e<4 -> h0[4q+e];  e>=4 -> h1[4q+e-4]
//   FC     K: e<4 -> h1[4q+e];  e>=4 -> 0
__global__
__attribute__((amdgpu_flat_work_group_size(256,256)))
__attribute__((amdgpu_waves_per_eu(1,4)))
void lstm_mfma_kernel(const float* __restrict__ in,
                      const float* __restrict__ Wih0, const float* __restrict__ Whh0,
                      const float* __restrict__ bih0, const float* __restrict__ bhh0,
                      const float* __restrict__ Wih1, const float* __restrict__ Whh1,
                      const float* __restrict__ bih1, const float* __restrict__ bhh1,
                      const float* __restrict__ Wfc,  const float* __restrict__ bfc,
                      float* __restrict__ out, int B)
{
    const int lane = threadIdx.x & 63;
    const int wid  = threadIdx.x >> 6;
    const int q  = lane >> 4;       // k-group / row-group
    const int sl = lane & 15;       // sample slot (MFMA col)
    const long s0 = (long)(blockIdx.x*4 + wid)*16;

    // ---- weight A-frags (VGPR-resident, hi/lo split), virtual-K layout ----
    bf16x8 a0h[4], a0l[4], a1h[4], a1l[4];
    f32x4 bias0[4], bias1[4];
    sfor<0,4>([&](auto MT){ constexpr int mt = MT.value;
        const int g = 16*mt + sl;                  // gate row (A row = sl)
        sfor<0,8>([&](auto E){ constexpr int e = E.value;
            float w0;
            if constexpr (e < 4) w0 = Whh0[g*16 + 4*q + e];
            else w0 = (q==0) ? Wih0[g*8 + (e-4)] : (q==1 ? Wih0[g*8 + e] : 0.f);
            a0h[mt][e] = (short)(__float_as_uint(w0)>>16);
            a0l[mt][e] = (short)(__float_as_uint(w0 - hi_part(w0))>>16);
            float w1;
            if constexpr (e < 4) w1 = Wih1[g*16 + 4*q + e];
            else                 w1 = Whh1[g*16 + 4*q + (e-4)];
            a1h[mt][e] = (short)(__float_as_uint(w1)>>16);
            a1l[mt][e] = (short)(__float_as_uint(w1 - hi_part(w1))>>16);
        });
        sfor<0,4>([&](auto R){ constexpr int r = R.value;
            const int gb = 16*mt + 4*q + r;        // C/D row = 4q+r
            bias0[mt][r] = bih0[gb] + bhh0[gb];
            bias1[mt][r] = bih1[gb] + bhh1[gb];
        });
    });

    // ---- state: packed h (hi/lo) + cell, all lane-local ----
    unsigned P0hi=0,Q0hi=0,P0lo=0,Q0lo=0;   // h0 units 4q..4q+3, sample sl
    unsigned P1hi=0,Q1hi=0,P1lo=0,Q1lo=0;   // h1
    f32x4 c0{0,0,0,0}, c1{0,0,0,0};

    // ---- x stream: lanes q<2 load float4 = x_t[sl][4q..4q+3]; rotate ----
    const float* xbase = in + (s0 + sl)*64 + q*4;
    float4 xv{0,0,0,0};
    if (q < 2) xv = *(const float4*)(xbase);

    sfor<0,8>([&](auto T){ constexpr int t = T.value;
        // prefetch next step's x while this step computes
        float4 xn{0,0,0,0};
        if constexpr (t < 7) { if (q < 2) xn = *(const float4*)(xbase + (t+1)*8); }

        unsigned xh0=0,xh1=0,xl0=0,xl1=0;
        if (q < 2) {
            xh0 = pk2(xv.x, xv.y);  xh1 = pk2(xv.z, xv.w);
            xl0 = pk2lo(xv.x, xv.y); xl1 = pk2lo(xv.z, xv.w);
        }

        // ================= layer 0 =================
        {
            bf16x8 Bh = mkB(P0hi, Q0hi, xh0, xh1);
            bf16x8 Bl = mkB(P0lo, Q0lo, xl0, xl1);
            f32x4 dd[4];
            sfor<0,4>([&](auto MT){ constexpr int mt = MT.value;
                f32x4 d = MFMA16(a0l[mt], Bh, bias0[mt], 0,0,0);
                d = MFMA16(a0h[mt], Bl, d, 0,0,0);
                d = MFMA16(a0h[mt], Bh, d, 0,0,0);
                dd[mt] = d;
            });
            f32x4 hv;
            sfor<0,4>([&](auto R){ constexpr int r = R.value;
                float iv = sigmoid_f(dd[0][r]);
                float fv = sigmoid_f(dd[1][r]);
                float gv = tanh_f   (dd[2][r]);
                float ov = sigmoid_f(dd[3][r]);
                float cn = fv*c0[r] + iv*gv;
                c0[r] = cn;
                hv[r] = ov * tanh_f(cn);
            });
            P0hi = pk2(hv[0],hv[1]);   Q0hi = pk2(hv[2],hv[3]);
            P0lo = pk2lo(hv[0],hv[1]); Q0lo = pk2lo(hv[2],hv[3]);
        }
        // ================= layer 1 =================
        {
            bf16x8 Bh = mkB(P0hi, Q0hi, P1hi, Q1hi);
            bf16x8 Bl = mkB(P0lo, Q0lo, P1lo, Q1lo);
            f32x4 dd[4];
            sfor<0,4>([&](auto MT){ constexpr int mt = MT.value;
                f32x4 d = MFMA16(a1l[mt], Bh, bias1[mt], 0,0,0);
                d = MFMA16(a1h[mt], Bl, d, 0,0,0);
                d = MFMA16(a1h[mt], Bh, d, 0,0,0);
                dd[mt] = d;
            });
            f32x4 hv;
            sfor<0,4>([&](auto R){ constexpr int r = R.value;
                float iv = sigmoid_f(dd[0][r]);
                float fv = sigmoid_f(dd[1][r]);
                float gv = tanh_f   (dd[2][r]);
                float ov = sigmoid_f(dd[3][r]);
                float cn = fv*c1[r] + iv*gv;
                c1[r] = cn;
                hv[r] = ov * tanh_f(cn);
            });
            P1hi = pk2(hv[0],hv[1]);   Q1hi = pk2(hv[2],hv[3]);
            P1lo = pk2lo(hv[0],hv[1]); Q1lo = pk2lo(hv[2],hv[3]);
        }
        xv = xn;
    });

    // ================= FC (weights loaded after the loop: no loop pressure) =
    {
        bf16x8 afh, afl;
        f32x4 biasf;
        sfor<0,8>([&](auto E){ constexpr int e = E.value;
            float wf = 0.f;
            if constexpr (e < 4) { if (sl < 10) wf = Wfc[sl*16 + 4*q + e]; }
            afh[e] = (short)(__float_as_uint(wf)>>16);
            afl[e] = (short)(__float_as_uint(wf - hi_part(wf))>>16);
        });
        sfor<0,4>([&](auto R){ constexpr int r = R.value;
            const int gb = 4*q + r;
            biasf[r] = (gb < 10) ? bfc[gb] : 0.f;
        });
        bf16x8 Bh = mkB(P1hi, Q1hi, 0u, 0u);
        bf16x8 Bl = mkB(P1lo, Q1lo, 0u, 0u);
        f32x4 d = MFMA16(afl, Bh, biasf, 0,0,0);
        d = MFMA16(afh, Bl, d, 0,0,0);
        d = MFMA16(afh, Bh, d, 0,0,0);
        // lane (q,sl) holds out[sample sl][class 4q+r]
        float* orow = out + (s0 + sl)*10;
        if (q == 0)      { *(float2*)(orow+0) = float2{d[0],d[1]}; *(float2*)(orow+2) = float2{d[2],d[3]}; }
        else if (q == 1) { *(float2*)(orow+4) = float2{d[0],d[1]}; *(float2*)(orow+6) = float2{d[2],d[3]}; }
        else if (q == 2) { *(float2*)(orow+8) = float2{d[0],d[1]}; }
    }
}

extern "C" void kernel_launch(void* const* d_in, const int* in_sizes, int n_in,
                              void* d_out, int out_size, void* d_ws, size_t ws_size,
                              hipStream_t stream) {
    const float* in   = (const float*)d_in[0];
    const float* Wih0 = (const float*)d_in[1];
    const float* Whh0 = (const float*)d_in[2];
    const float* bih0 = (const float*)d_in[3];
    const float* bhh0 = (const float*)d_in[4];
    const float* Wih1 = (const float*)d_in[5];
    const float* Whh1 = (const float*)d_in[6];
    const float* bih1 = (const float*)d_in[7];
    const float* bhh1 = (const float*)d_in[8];
    const float* Wfc  = (const float*)d_in[9];
    const float* bfc  = (const float*)d_in[10];
    float* out = (float*)d_out;

    int B = in_sizes[0] / 64;           // 262144 samples
    int grid = B / 64;                  // 16 samples/wave * 4 waves/block
    lstm_mfma_kernel<<<grid, 256, 0, stream>>>(in, Wih0, Whh0, bih0, bhh0,
                                               Wih1, Whh1, bih1, bhh1,
                                               Wfc, bfc, out, B);
}

// Round 10
// 122.418 us; speedup vs baseline: 16.0146x; 1.1637x over previous
//
#include <hip/hip_runtime.h>

#define LOG2E 1.44269504088896340736f

typedef short bf16x8 __attribute__((ext_vector_type(8)));
typedef float f32x4  __attribute__((ext_vector_type(4)));

template <int I> struct IntC { static constexpr int value = I; };
template <int I, int N, typename F>
__device__ __forceinline__ void sfor(F&& f) {
    if constexpr (I < N) { f(IntC<I>{}); sfor<I + 1, N>(f); }
}

__device__ __forceinline__ float fexp2(float x){ return __builtin_amdgcn_exp2f(x); }
__device__ __forceinline__ float frcp(float x){ return __builtin_amdgcn_rcpf(x); }
__device__ __forceinline__ float sigmoid_f(float x){ return frcp(1.f + fexp2(-x*LOG2E)); }
__device__ __forceinline__ float tanh_f(float x){ float t = fexp2(x*(2.f*LOG2E)); return (t-1.f)*frcp(t+1.f); }

__device__ __forceinline__ float hi_part(float x){
    return __uint_as_float(__float_as_uint(x) & 0xFFFF0000u);
}
__device__ __forceinline__ unsigned pk2(float a, float b){   // low16=bf16(a), high16=bf16(b)
    return (__float_as_uint(a)>>16) | (__float_as_uint(b)&0xFFFF0000u);
}
__device__ __forceinline__ unsigned pk2lo(float a, float b){ // packed residuals
    return pk2(a - hi_part(a), b - hi_part(b));
}
__device__ __forceinline__ bf16x8 mkB(unsigned d0,unsigned d1,unsigned d2,unsigned d3){
    uint4 u{d0,d1,d2,d3};
    return __builtin_bit_cast(bf16x8, u);
}

#define MFMA16 __builtin_amdgcn_mfma_f32_16x16x32_bf16

// One wave = 32 samples (2 groups of 16), ZERO LDS. Virtual-K permutation:
// lane (q,sl) owns C/D rows 4q..4q+3 of sample sl; B element k=8q+e is that
// lane's own packed h (and x) registers. A loaded with matching permutation.
//   layer0 K: e<4 -> h0[4q+e];  e>=4: q==0 -> x[e-4], q==1 -> x[e], else 0
//   layer1 K: e<4 -> h0[4q+e];  e>=4 -> h1[4q+e-4]
//   FC     K: e<4 -> h1[4q+e];  e>=4 -> 0
// Two groups interleave in the t-loop: group B's MFMA/activation chain fills
// group A's latency (round-9 diagnosis: serial phase chain + thin TLP), and
// the weight prologue (~150 loads + ~500 converts) amortizes over 32 samples.
__global__
__attribute__((amdgpu_flat_work_group_size(256,256)))
__attribute__((amdgpu_waves_per_eu(1,8)))
void lstm_mfma_kernel(const float* __restrict__ in,
                      const float* __restrict__ Wih0, const float* __restrict__ Whh0,
                      const float* __restrict__ bih0, const float* __restrict__ bhh0,
                      const float* __restrict__ Wih1, const float* __restrict__ Whh1,
                      const float* __restrict__ bih1, const float* __restrict__ bhh1,
                      const float* __restrict__ Wfc,  const float* __restrict__ bfc,
                      float* __restrict__ out, int B)
{
    const int lane = threadIdx.x & 63;
    const int wid  = threadIdx.x >> 6;
    const int q  = lane >> 4;       // k-group / row-group
    const int sl = lane & 15;       // sample slot (MFMA col)
    const long s0 = (long)(blockIdx.x*4 + wid)*32;

    // ---- weight A-frags (VGPR-resident, hi/lo split), virtual-K layout ----
    bf16x8 a0h[4], a0l[4], a1h[4], a1l[4];
    f32x4 bias0[4], bias1[4];
    sfor<0,4>([&](auto MT){ constexpr int mt = MT.value;
        const int g = 16*mt + sl;                  // gate row (A row = sl)
        sfor<0,8>([&](auto E){ constexpr int e = E.value;
            float w0;
            if constexpr (e < 4) w0 = Whh0[g*16 + 4*q + e];
            else w0 = (q==0) ? Wih0[g*8 + (e-4)] : (q==1 ? Wih0[g*8 + e] : 0.f);
            a0h[mt][e] = (short)(__float_as_uint(w0)>>16);
            a0l[mt][e] = (short)(__float_as_uint(w0 - hi_part(w0))>>16);
            float w1;
            if constexpr (e < 4) w1 = Wih1[g*16 + 4*q + e];
            else                 w1 = Whh1[g*16 + 4*q + (e-4)];
            a1h[mt][e] = (short)(__float_as_uint(w1)>>16);
            a1l[mt][e] = (short)(__float_as_uint(w1 - hi_part(w1))>>16);
        });
        sfor<0,4>([&](auto R){ constexpr int r = R.value;
            const int gb = 16*mt + 4*q + r;        // C/D row = 4q+r
            bias0[mt][r] = bih0[gb] + bhh0[gb];
            bias1[mt][r] = bih1[gb] + bhh1[gb];
        });
    });

    // ---- state ×2 groups: packed h (hi/lo) + cell, all lane-local ----
    unsigned P0hi[2]={0,0}, Q0hi[2]={0,0}, P0lo[2]={0,0}, Q0lo[2]={0,0};
    unsigned P1hi[2]={0,0}, Q1hi[2]={0,0}, P1lo[2]={0,0}, Q1lo[2]={0,0};
    f32x4 c0[2], c1[2];
    sfor<0,2>([&](auto G){ constexpr int g=G.value;
        c0[g] = f32x4{0,0,0,0}; c1[g] = f32x4{0,0,0,0};
    });

    // ---- x stream: lanes q<2 load float4 = x_t[sample][4q..4q+3]; rotate ----
    float4 xv[2];
    sfor<0,2>([&](auto G){ constexpr int g=G.value;
        xv[g] = float4{0,0,0,0};
        if (q < 2) xv[g] = *(const float4*)(in + (s0 + g*16 + sl)*64 + q*4);
    });

    sfor<0,8>([&](auto T){ constexpr int t = T.value;
        // prefetch next step's x while this step computes
        float4 xn[2];
        sfor<0,2>([&](auto G){ constexpr int g=G.value;
            xn[g] = float4{0,0,0,0};
            if constexpr (t < 7) {
                if (q < 2) xn[g] = *(const float4*)(in + (s0 + g*16 + sl)*64 + q*4 + (t+1)*8);
            }
        });

        // ================= layer 0 (both groups: independent chains) ========
        sfor<0,2>([&](auto G){ constexpr int g=G.value;
            unsigned xh0=0,xh1=0,xl0=0,xl1=0;
            if (q < 2) {
                xh0 = pk2(xv[g].x, xv[g].y);   xh1 = pk2(xv[g].z, xv[g].w);
                xl0 = pk2lo(xv[g].x, xv[g].y); xl1 = pk2lo(xv[g].z, xv[g].w);
            }
            bf16x8 Bh = mkB(P0hi[g], Q0hi[g], xh0, xh1);
            bf16x8 Bl = mkB(P0lo[g], Q0lo[g], xl0, xl1);
            f32x4 dd[4];
            sfor<0,4>([&](auto MT){ constexpr int mt = MT.value;
                f32x4 d = MFMA16(a0l[mt], Bh, bias0[mt], 0,0,0);
                d = MFMA16(a0h[mt], Bl, d, 0,0,0);
                d = MFMA16(a0h[mt], Bh, d, 0,0,0);
                dd[mt] = d;
            });
            f32x4 hv;
            sfor<0,4>([&](auto R){ constexpr int r = R.value;
                float iv = sigmoid_f(dd[0][r]);
                float fv = sigmoid_f(dd[1][r]);
                float gv = tanh_f   (dd[2][r]);
                float ov = sigmoid_f(dd[3][r]);
                float cn = fv*c0[g][r] + iv*gv;
                c0[g][r] = cn;
                hv[r] = ov * tanh_f(cn);
            });
            P0hi[g] = pk2(hv[0],hv[1]);   Q0hi[g] = pk2(hv[2],hv[3]);
            P0lo[g] = pk2lo(hv[0],hv[1]); Q0lo[g] = pk2lo(hv[2],hv[3]);
        });

        // ================= layer 1 (both groups) ============================
        sfor<0,2>([&](auto G){ constexpr int g=G.value;
            bf16x8 Bh = mkB(P0hi[g], Q0hi[g], P1hi[g], Q1hi[g]);
            bf16x8 Bl = mkB(P0lo[g], Q0lo[g], P1lo[g], Q1lo[g]);
            f32x4 dd[4];
            sfor<0,4>([&](auto MT){ constexpr int mt = MT.value;
                f32x4 d = MFMA16(a1l[mt], Bh, bias1[mt], 0,0,0);
                d = MFMA16(a1h[mt], Bl, d, 0,0,0);
                d = MFMA16(a1h[mt], Bh, d, 0,0,0);
                dd[mt] = d;
            });
            f32x4 hv;
            sfor<0,4>([&](auto R){ constexpr int r = R.value;
                float iv = sigmoid_f(dd[0][r]);
                float fv = sigmoid_f(dd[1][r]);
                float gv = tanh_f   (dd[2][r]);
                float ov = sigmoid_f(dd[3][r]);
                float cn = fv*c1[g][r] + iv*gv;
                c1[g][r] = cn;
                hv[r] = ov * tanh_f(cn);
            });
            P1hi[g] = pk2(hv[0],hv[1]);   Q1hi[g] = pk2(hv[2],hv[3]);
            P1lo[g] = pk2lo(hv[0],hv[1]); Q1lo[g] = pk2lo(hv[2],hv[3]);
        });

        sfor<0,2>([&](auto G){ constexpr int g=G.value; xv[g] = xn[g]; });
    });

    // ================= FC (weights loaded after the loop) ===================
    {
        bf16x8 afh, afl;
        f32x4 biasf;
        sfor<0,8>([&](auto E){ constexpr int e = E.value;
            float wf = 0.f;
            if constexpr (e < 4) { if (sl < 10) wf = Wfc[sl*16 + 4*q + e]; }
            afh[e] = (short)(__float_as_uint(wf)>>16);
            afl[e] = (short)(__float_as_uint(wf - hi_part(wf))>>16);
        });
        sfor<0,4>([&](auto R){ constexpr int r = R.value;
            const int gb = 4*q + r;
            biasf[r] = (gb < 10) ? bfc[gb] : 0.f;
        });
        sfor<0,2>([&](auto G){ constexpr int g=G.value;
            bf16x8 Bh = mkB(P1hi[g], Q1hi[g], 0u, 0u);
            bf16x8 Bl = mkB(P1lo[g], Q1lo[g], 0u, 0u);
            f32x4 d = MFMA16(afl, Bh, biasf, 0,0,0);
            d = MFMA16(afh, Bl, d, 0,0,0);
            d = MFMA16(afh, Bh, d, 0,0,0);
            // lane (q,sl) holds out[sample g*16+sl][class 4q+r]
            float* orow = out + (s0 + g*16 + sl)*10;
            if (q == 0)      { *(float2*)(orow+0) = float2{d[0],d[1]}; *(float2*)(orow+2) = float2{d[2],d[3]}; }
            else if (q == 1) { *(float2*)(orow+4) = float2{d[0],d[1]}; *(float2*)(orow+6) = float2{d[2],d[3]}; }
            else if (q == 2) { *(float2*)(orow+8) = float2{d[0],d[1]}; }
        });
    }
}

extern "C" void kernel_launch(void* const* d_in, const int* in_sizes, int n_in,
                              void* d_out, int out_size, void* d_ws, size_t ws_size,
                              hipStream_t stream) {
    const float* in   = (const float*)d_in[0];
    const float* Wih0 = (const float*)d_in[1];
    const float* Whh0 = (const float*)d_in[2];
    const float* bih0 = (const float*)d_in[3];
    const float* bhh0 = (const float*)d_in[4];
    const float* Wih1 = (const float*)d_in[5];
    const float* Whh1 = (const float*)d_in[6];
    const float* bih1 = (const float*)d_in[7];
    const float* bhh1 = (const float*)d_in[8];
    const float* Wfc  = (const float*)d_in[9];
    const float* bfc  = (const float*)d_in[10];
    float* out = (float*)d_out;

    int B = in_sizes[0] / 64;           // 262144 samples
    int grid = B / 128;                 // 32 samples/wave * 4 waves/block
    lstm_mfma_kernel<<<grid, 256, 0, stream>>>(in, Wih0, Whh0, bih0, bhh0,
                                               Wih1, Whh1, bih1, bhh1,
                                               Wfc, bfc, out, B);
}

// Round 11
// 105.025 us; speedup vs baseline: 18.6667x; 1.1656x over previous
//
#include <hip/hip_runtime.h>

#define LOG2E 1.44269504088896340736f

typedef short bf16x8 __attribute__((ext_vector_type(8)));
typedef float f32x4  __attribute__((ext_vector_type(4)));

template <int I> struct IntC { static constexpr int value = I; };
template <int I, int N, typename F>
__device__ __forceinline__ void sfor(F&& f) {
    if constexpr (I < N) { f(IntC<I>{}); sfor<I + 1, N>(f); }
}

__device__ __forceinline__ float fexp2(float x){ return __builtin_amdgcn_exp2f(x); }
__device__ __forceinline__ float frcp(float x){ return __builtin_amdgcn_rcpf(x); }
__device__ __forceinline__ float sigmoid_f(float x){ return frcp(1.f + fexp2(-x*LOG2E)); }
__device__ __forceinline__ float tanh_f(float x){ float t = fexp2(x*(2.f*LOG2E)); return (t-1.f)*frcp(t+1.f); }

__device__ __forceinline__ float hi_part(float x){
    return __uint_as_float(__float_as_uint(x) & 0xFFFF0000u);
}
// pk2(a,b): low16 = bf16trunc(a), high16 = bf16trunc(b) -> single v_perm_b32:
// result bytes [a2,a3,b2,b3]; perm(S0=hi=b, S1=lo=a, sel bytes [2,3,6,7]).
__device__ __forceinline__ unsigned pk2(float a, float b){
    return __builtin_amdgcn_perm(__float_as_uint(b), __float_as_uint(a), 0x07060302u);
}
__device__ __forceinline__ unsigned pk2lo(float a, float b){ // packed residuals
    return pk2(a - hi_part(a), b - hi_part(b));
}
__device__ __forceinline__ bf16x8 mkB(unsigned d0,unsigned d1,unsigned d2,unsigned d3){
    uint4 u{d0,d1,d2,d3};
    return __builtin_bit_cast(bf16x8, u);
}

#define MFMA16 __builtin_amdgcn_mfma_f32_16x16x32_bf16

// One wave = 64 samples (4 groups of 16), ZERO LDS. Virtual-K permutation:
// lane (q,sl) owns C/D rows 4q..4q+3 of sample sl; B element k=8q+e is that
// lane's own packed registers. A loaded with the matching permutation.
//   layer0 K: e<4 -> h0[4q+e]; e==4,5 -> x[2q],x[2q+1]; e>=6 -> 0
//   layer1 K: e<4 -> h0[4q+e]; e>=4 -> h1[4q+e-4]
//   FC     K: e<4 -> h1[4q+e]; e>=4 -> 0
// 4 groups interleave in the t-loop: 16 independent MFMA chains + 4 trans
// chains fill the serial phase latency (round-10 diagnosis: 2.3x issue-floor
// gap from exposed latency); prologue amortized over 64 samples.
__global__
__attribute__((amdgpu_flat_work_group_size(256,256)))
__attribute__((amdgpu_waves_per_eu(1,8)))
void lstm_mfma_kernel(const float* __restrict__ in,
                      const float* __restrict__ Wih0, const float* __restrict__ Whh0,
                      const float* __restrict__ bih0, const float* __restrict__ bhh0,
                      const float* __restrict__ Wih1, const float* __restrict__ Whh1,
                      const float* __restrict__ bih1, const float* __restrict__ bhh1,
                      const float* __restrict__ Wfc,  const float* __restrict__ bfc,
                      float* __restrict__ out, int B)
{
    const int lane = threadIdx.x & 63;
    const int wid  = threadIdx.x >> 6;
    const int q  = lane >> 4;       // k-group / row-group
    const int sl = lane & 15;       // sample slot (MFMA col)
    const long s0 = (long)(blockIdx.x*4 + wid)*64;

    // ---- weight A-frags (VGPR-resident, hi/lo split), virtual-K layout ----
    bf16x8 a0h[4], a0l[4], a1h[4], a1l[4];
    f32x4 bias0[4], bias1[4];
    sfor<0,4>([&](auto MT){ constexpr int mt = MT.value;
        const int gr = 16*mt + sl;                 // gate row (A row = sl)
        sfor<0,8>([&](auto E){ constexpr int e = E.value;
            float w0;
            if constexpr (e < 4)      w0 = Whh0[gr*16 + 4*q + e];
            else if constexpr (e < 6) w0 = Wih0[gr*8 + 2*q + (e-4)];
            else                      w0 = 0.f;
            a0h[mt][e] = (short)(__float_as_uint(w0)>>16);
            a0l[mt][e] = (short)(__float_as_uint(w0 - hi_part(w0))>>16);
            float w1;
            if constexpr (e < 4) w1 = Wih1[gr*16 + 4*q + e];
            else                 w1 = Whh1[gr*16 + 4*q + (e-4)];
            a1h[mt][e] = (short)(__float_as_uint(w1)>>16);
            a1l[mt][e] = (short)(__float_as_uint(w1 - hi_part(w1))>>16);
        });
        sfor<0,4>([&](auto R){ constexpr int r = R.value;
            const int gb = 16*mt + 4*q + r;        // C/D row = 4q+r
            bias0[mt][r] = bih0[gb] + bhh0[gb];
            bias1[mt][r] = bih1[gb] + bhh1[gb];
        });
    });

    // ---- state x4 groups: packed h (hi/lo) + cell, all lane-local ----
    unsigned P0hi[4]={0,0,0,0}, Q0hi[4]={0,0,0,0}, P0lo[4]={0,0,0,0}, Q0lo[4]={0,0,0,0};
    unsigned P1hi[4]={0,0,0,0}, Q1hi[4]={0,0,0,0}, P1lo[4]={0,0,0,0}, Q1lo[4]={0,0,0,0};
    f32x4 c0[4], c1[4];
    sfor<0,4>([&](auto G){ constexpr int g=G.value;
        c0[g] = f32x4{0,0,0,0}; c1[g] = f32x4{0,0,0,0};
    });

    // ---- x stream: EVERY lane loads float2 = x_t[sample][2q..2q+1] ----
    // (group g's samples are s0 + g*16 + sl; per-group byte offset g*4096)
    const float* xbase = in + (s0 + sl)*64 + 2*q;
    float2 xv[4];
    sfor<0,4>([&](auto G){ constexpr int g=G.value;
        xv[g] = *(const float2*)(xbase + g*1024);
    });

#pragma unroll 2
    for (int t = 0; t < 8; ++t) {
        // prefetch next step's x (t==7: reload t=0, discarded — stays in bounds)
        const int nxt = (t==7) ? 0 : (t+1)*8;
        float2 xn[4];
        sfor<0,4>([&](auto G){ constexpr int g=G.value;
            xn[g] = *(const float2*)(xbase + g*1024 + nxt);
        });

        // ================= layer 0 (4 groups: independent chains) ==========
        sfor<0,4>([&](auto G){ constexpr int g=G.value;
            const unsigned xh = pk2(xv[g].x, xv[g].y);
            const unsigned xl = pk2lo(xv[g].x, xv[g].y);
            bf16x8 Bh = mkB(P0hi[g], Q0hi[g], xh, 0u);
            bf16x8 Bl = mkB(P0lo[g], Q0lo[g], xl, 0u);
            f32x4 dd[4];
            sfor<0,4>([&](auto MT){ constexpr int mt = MT.value;
                f32x4 d = MFMA16(a0l[mt], Bh, bias0[mt], 0,0,0);
                d = MFMA16(a0h[mt], Bl, d, 0,0,0);
                d = MFMA16(a0h[mt], Bh, d, 0,0,0);
                dd[mt] = d;
            });
            f32x4 hv;
            sfor<0,4>([&](auto R){ constexpr int r = R.value;
                float iv = sigmoid_f(dd[0][r]);
                float fv = sigmoid_f(dd[1][r]);
                float gv = tanh_f   (dd[2][r]);
                float ov = sigmoid_f(dd[3][r]);
                float cn = fv*c0[g][r] + iv*gv;
                c0[g][r] = cn;
                hv[r] = ov * tanh_f(cn);
            });
            P0hi[g] = pk2(hv[0],hv[1]);   Q0hi[g] = pk2(hv[2],hv[3]);
            P0lo[g] = pk2lo(hv[0],hv[1]); Q0lo[g] = pk2lo(hv[2],hv[3]);
        });

        // ================= layer 1 (4 groups) ==============================
        sfor<0,4>([&](auto G){ constexpr int g=G.value;
            bf16x8 Bh = mkB(P0hi[g], Q0hi[g], P1hi[g], Q1hi[g]);
            bf16x8 Bl = mkB(P0lo[g], Q0lo[g], P1lo[g], Q1lo[g]);
            f32x4 dd[4];
            sfor<0,4>([&](auto MT){ constexpr int mt = MT.value;
                f32x4 d = MFMA16(a1l[mt], Bh, bias1[mt], 0,0,0);
                d = MFMA16(a1h[mt], Bl, d, 0,0,0);
                d = MFMA16(a1h[mt], Bh, d, 0,0,0);
                dd[mt] = d;
            });
            f32x4 hv;
            sfor<0,4>([&](auto R){ constexpr int r = R.value;
                float iv = sigmoid_f(dd[0][r]);
                float fv = sigmoid_f(dd[1][r]);
                float gv = tanh_f   (dd[2][r]);
                float ov = sigmoid_f(dd[3][r]);
                float cn = fv*c1[g][r] + iv*gv;
                c1[g][r] = cn;
                hv[r] = ov * tanh_f(cn);
            });
            P1hi[g] = pk2(hv[0],hv[1]);   Q1hi[g] = pk2(hv[2],hv[3]);
            P1lo[g] = pk2lo(hv[0],hv[1]); Q1lo[g] = pk2lo(hv[2],hv[3]);
        });

        sfor<0,4>([&](auto G){ constexpr int g=G.value; xv[g] = xn[g]; });
    }

    // ================= FC (weights loaded after the loop) ===================
    {
        bf16x8 afh, afl;
        f32x4 biasf;
        sfor<0,8>([&](auto E){ constexpr int e = E.value;
            float wf = 0.f;
            if constexpr (e < 4) { if (sl < 10) wf = Wfc[sl*16 + 4*q + e]; }
            afh[e] = (short)(__float_as_uint(wf)>>16);
            afl[e] = (short)(__float_as_uint(wf - hi_part(wf))>>16);
        });
        sfor<0,4>([&](auto R){ constexpr int r = R.value;
            const int gb = 4*q + r;
            biasf[r] = (gb < 10) ? bfc[gb] : 0.f;
        });
        sfor<0,4>([&](auto G){ constexpr int g=G.value;
            bf16x8 Bh = mkB(P1hi[g], Q1hi[g], 0u, 0u);
            bf16x8 Bl = mkB(P1lo[g], Q1lo[g], 0u, 0u);
            f32x4 d = MFMA16(afl, Bh, biasf, 0,0,0);
            d = MFMA16(afh, Bl, d, 0,0,0);
            d = MFMA16(afh, Bh, d, 0,0,0);
            // lane (q,sl) holds out[sample g*16+sl][class 4q+r]
            float* orow = out + (s0 + g*16 + sl)*10;
            if (q == 0)      { *(float2*)(orow+0) = float2{d[0],d[1]}; *(float2*)(orow+2) = float2{d[2],d[3]}; }
            else if (q == 1) { *(float2*)(orow+4) = float2{d[0],d[1]}; *(float2*)(orow+6) = float2{d[2],d[3]}; }
            else if (q == 2) { *(float2*)(orow+8) = float2{d[0],d[1]}; }
        });
    }
}

extern "C" void kernel_launch(void* const* d_in, const int* in_sizes, int n_in,
                              void* d_out, int out_size, void* d_ws, size_t ws_size,
                              hipStream_t stream) {
    const float* in   = (const float*)d_in[0];
    const float* Wih0 = (const float*)d_in[1];
    const float* Whh0 = (const float*)d_in[2];
    const float* bih0 = (const float*)d_in[3];
    const float* bhh0 = (const float*)d_in[4];
    const float* Wih1 = (const float*)d_in[5];
    const float* Whh1 = (const float*)d_in[6];
    const float* bih1 = (const float*)d_in[7];
    const float* bhh1 = (const float*)d_in[8];
    const float* Wfc  = (const float*)d_in[9];
    const float* bfc  = (const float*)d_in[10];
    float* out = (float*)d_out;

    int B = in_sizes[0] / 64;           // 262144 samples
    int grid = B / 256;                 // 64 samples/wave * 4 waves/block
    lstm_mfma_kernel<<<grid, 256, 0, stream>>>(in, Wih0, Whh0, bih0, bhh0,
                                               Wih1, Whh1, bih1, bhh1,
                                               Wfc, bfc, out, B);
}

// Round 12
// 100.722 us; speedup vs baseline: 19.4643x; 1.0427x over previous
//
#include <hip/hip_runtime.h>

#define LOG2E 1.44269504088896340736f

typedef short bf16x8 __attribute__((ext_vector_type(8)));
typedef float f32x4  __attribute__((ext_vector_type(4)));

template <int I> struct IntC { static constexpr int value = I; };
template <int I, int N, typename F>
__device__ __forceinline__ void sfor(F&& f) {
    if constexpr (I < N) { f(IntC<I>{}); sfor<I + 1, N>(f); }
}

__device__ __forceinline__ float fexp2(float x){ return __builtin_amdgcn_exp2f(x); }
__device__ __forceinline__ float frcp(float x){ return __builtin_amdgcn_rcpf(x); }

__device__ __forceinline__ float hi_part(float x){
    return __uint_as_float(__float_as_uint(x) & 0xFFFF0000u);
}
// pk2(a,b): low16 = bf16trunc(a), high16 = bf16trunc(b) -> single v_perm_b32.
__device__ __forceinline__ unsigned pk2(float a, float b){
    return __builtin_amdgcn_perm(__float_as_uint(b), __float_as_uint(a), 0x07060302u);
}
__device__ __forceinline__ unsigned pk2lo(float a, float b){
    return pk2(a - hi_part(a), b - hi_part(b));
}
__device__ __forceinline__ bf16x8 mkB(unsigned d0,unsigned d1,unsigned d2,unsigned d3){
    uint4 u{d0,d1,d2,d3};
    return __builtin_bit_cast(bf16x8, u);
}

#define MFMA16 __builtin_amdgcn_mfma_f32_16x16x32_bf16

// LSTM cell tail. dd[mt] holds SCALED preacts: i',f',o' = -log2e*pre,
// g' = 2log2e*pre (scales folded into MFMA weights+biases).
//   sigma(pre) = 1/(1+exp2(-L*pre)) = 1/(1+E)
//   tanh(pre)  = (exp2(2L*pre)-1)/(exp2(2L*pre)+1) = (E-1)/(E+1)
// Reciprocals batched: gate pairs (2 rcp + 6 mul replaces 4 rcp, products
// <= 2^72: overflow-safe), tanh(c) quad across rows (1 rcp + 9 mul).
__device__ __forceinline__ f32x4 cell_tail(const f32x4 (&dd)[4], f32x4& c){
    f32x4 Ei, Ef, Eg, Eo;
    sfor<0,4>([&](auto R){ constexpr int r=R.value;
        Ei[r] = fexp2(dd[0][r]);
        Ef[r] = fexp2(dd[1][r]);
        Eg[r] = fexp2(dd[2][r]);
        Eo[r] = fexp2(dd[3][r]);
    });
    f32x4 ov, cn;
    sfor<0,4>([&](auto R){ constexpr int r=R.value;
        float Ai = 1.f + Ei[r], Af = 1.f + Ef[r];
        float Ag = 1.f + Eg[r], Ao = 1.f + Eo[r];
        float p  = Ai*Af;  float rp = frcp(p);
        float iv = Af*rp;                 // 1/Ai = sigma(i)
        float fv = Ai*rp;                 // 1/Af = sigma(f)
        float q2 = Ag*Ao;  float rq = frcp(q2);
        float gr = Ao*rq;                 // 1/Ag
        ov[r]    = Ag*rq;                 // 1/Ao = sigma(o)
        float gv = (Eg[r]-1.f)*gr;        // tanh(g)
        cn[r] = fv*c[r] + iv*gv;
    });
    c = cn;
    // tanh(cn), rcp quad-batched across the 4 rows (tc <= 2^23, P4 <= 2^92)
    f32x4 tc;
    sfor<0,4>([&](auto R){ constexpr int r=R.value;
        tc[r] = fexp2(cn[r]*(2.f*LOG2E));
    });
    float B0=tc[0]+1.f, B1=tc[1]+1.f, B2=tc[2]+1.f, B3=tc[3]+1.f;
    float P2=B0*B1, P3=P2*B2, P4=P3*B3;
    float r4=frcp(P4);
    float R3=P3*r4;          // 1/B3
    float r3=B3*r4;
    float R2=P2*r3;          // 1/B2
    float r2=B2*r3;
    float R1=B0*r2;          // 1/B1
    float R0=B1*r2;          // 1/B0
    f32x4 hv;
    hv[0] = ov[0]*((tc[0]-1.f)*R0);
    hv[1] = ov[1]*((tc[1]-1.f)*R1);
    hv[2] = ov[2]*((tc[2]-1.f)*R2);
    hv[3] = ov[3]*((tc[3]-1.f)*R3);
    return hv;
}

// One wave = 64 samples (4 groups of 16), ZERO LDS. Virtual-K permutation:
// lane (q,sl) owns C/D rows 4q..4q+3 of sample sl; B element k=8q+e is that
// lane's own packed registers. A loaded with the matching permutation.
//   layer0 K: e<4 -> h0[4q+e]; e==4,5 -> x[2q],x[2q+1]; e>=6 -> 0
//   layer1 K: e<4 -> h0[4q+e]; e>=4 -> h1[4q+e-4]
//   FC     K: e<4 -> h1[4q+e]; e>=4 -> 0
__global__
__attribute__((amdgpu_flat_work_group_size(256,256)))
__attribute__((amdgpu_waves_per_eu(1,8)))
void lstm_mfma_kernel(const float* __restrict__ in,
                      const float* __restrict__ Wih0, const float* __restrict__ Whh0,
                      const float* __restrict__ bih0, const float* __restrict__ bhh0,
                      const float* __restrict__ Wih1, const float* __restrict__ Whh1,
                      const float* __restrict__ bih1, const float* __restrict__ bhh1,
                      const float* __restrict__ Wfc,  const float* __restrict__ bfc,
                      float* __restrict__ out, int B)
{
    const int lane = threadIdx.x & 63;
    const int wid  = threadIdx.x >> 6;
    const int q  = lane >> 4;       // k-group / row-group
    const int sl = lane & 15;       // sample slot (MFMA col)
    const long s0 = (long)(blockIdx.x*4 + wid)*64;

    // ---- weight A-frags (VGPR-resident, hi/lo split), virtual-K layout,
    //      exp-scale folded in per gate: mt==2 (g): +2*log2e, else -log2e ----
    bf16x8 a0h[4], a0l[4], a1h[4], a1l[4];
    f32x4 bias0[4], bias1[4];
    sfor<0,4>([&](auto MT){ constexpr int mt = MT.value;
        constexpr float SC = (mt==2) ? (2.f*LOG2E) : (-LOG2E);
        const int gr = 16*mt + sl;                 // gate row (A row = sl)
        sfor<0,8>([&](auto E){ constexpr int e = E.value;
            float w0;
            if constexpr (e < 4)      w0 = Whh0[gr*16 + 4*q + e];
            else if constexpr (e < 6) w0 = Wih0[gr*8 + 2*q + (e-4)];
            else                      w0 = 0.f;
            w0 *= SC;
            a0h[mt][e] = (short)(__float_as_uint(w0)>>16);
            a0l[mt][e] = (short)(__float_as_uint(w0 - hi_part(w0))>>16);
            float w1;
            if constexpr (e < 4) w1 = Wih1[gr*16 + 4*q + e];
            else                 w1 = Whh1[gr*16 + 4*q + (e-4)];
            w1 *= SC;
            a1h[mt][e] = (short)(__float_as_uint(w1)>>16);
            a1l[mt][e] = (short)(__float_as_uint(w1 - hi_part(w1))>>16);
        });
        sfor<0,4>([&](auto R){ constexpr int r = R.value;
            const int gb = 16*mt + 4*q + r;        // C/D row = 4q+r
            bias0[mt][r] = (bih0[gb] + bhh0[gb]) * SC;
            bias1[mt][r] = (bih1[gb] + bhh1[gb]) * SC;
        });
    });

    // ---- state x4 groups: packed h (hi/lo) + cell, all lane-local ----
    unsigned P0hi[4]={0,0,0,0}, Q0hi[4]={0,0,0,0}, P0lo[4]={0,0,0,0}, Q0lo[4]={0,0,0,0};
    unsigned P1hi[4]={0,0,0,0}, Q1hi[4]={0,0,0,0}, P1lo[4]={0,0,0,0}, Q1lo[4]={0,0,0,0};
    f32x4 c0[4], c1[4];
    sfor<0,4>([&](auto G){ constexpr int g=G.value;
        c0[g] = f32x4{0,0,0,0}; c1[g] = f32x4{0,0,0,0};
    });

    // ---- x stream: EVERY lane loads float2 = x_t[sample][2q..2q+1] ----
    const float* xbase = in + (s0 + sl)*64 + 2*q;
    float2 xv[4];
    sfor<0,4>([&](auto G){ constexpr int g=G.value;
        xv[g] = *(const float2*)(xbase + g*1024);
    });

#pragma unroll 2
    for (int t = 0; t < 8; ++t) {
        // prefetch next step's x (t==7: reload t=0, discarded — in bounds)
        const int nxt = (t==7) ? 0 : (t+1)*8;
        float2 xn[4];
        sfor<0,4>([&](auto G){ constexpr int g=G.value;
            xn[g] = *(const float2*)(xbase + g*1024 + nxt);
        });

        // ================= layer 0 (4 groups: independent chains) ==========
        sfor<0,4>([&](auto G){ constexpr int g=G.value;
            const unsigned xh = pk2(xv[g].x, xv[g].y);
            const unsigned xl = pk2lo(xv[g].x, xv[g].y);
            bf16x8 Bh = mkB(P0hi[g], Q0hi[g], xh, 0u);
            bf16x8 Bl = mkB(P0lo[g], Q0lo[g], xl, 0u);
            f32x4 dd[4];
            sfor<0,4>([&](auto MT){ constexpr int mt = MT.value;
                f32x4 d = MFMA16(a0l[mt], Bh, bias0[mt], 0,0,0);
                d = MFMA16(a0h[mt], Bl, d, 0,0,0);
                d = MFMA16(a0h[mt], Bh, d, 0,0,0);
                dd[mt] = d;
            });
            f32x4 hv = cell_tail(dd, c0[g]);
            P0hi[g] = pk2(hv[0],hv[1]);   Q0hi[g] = pk2(hv[2],hv[3]);
            P0lo[g] = pk2lo(hv[0],hv[1]); Q0lo[g] = pk2lo(hv[2],hv[3]);
        });

        // ================= layer 1 (4 groups) ==============================
        sfor<0,4>([&](auto G){ constexpr int g=G.value;
            bf16x8 Bh = mkB(P0hi[g], Q0hi[g], P1hi[g], Q1hi[g]);
            bf16x8 Bl = mkB(P0lo[g], Q0lo[g], P1lo[g], Q1lo[g]);
            f32x4 dd[4];
            sfor<0,4>([&](auto MT){ constexpr int mt = MT.value;
                f32x4 d = MFMA16(a1l[mt], Bh, bias1[mt], 0,0,0);
                d = MFMA16(a1h[mt], Bl, d, 0,0,0);
                d = MFMA16(a1h[mt], Bh, d, 0,0,0);
                dd[mt] = d;
            });
            f32x4 hv = cell_tail(dd, c1[g]);
            P1hi[g] = pk2(hv[0],hv[1]);   Q1hi[g] = pk2(hv[2],hv[3]);
            P1lo[g] = pk2lo(hv[0],hv[1]); Q1lo[g] = pk2lo(hv[2],hv[3]);
        });

        sfor<0,4>([&](auto G){ constexpr int g=G.value; xv[g] = xn[g]; });
    }

    // ================= FC (weights loaded after the loop; UNSCALED) ========
    {
        bf16x8 afh, afl;
        f32x4 biasf;
        sfor<0,8>([&](auto E){ constexpr int e = E.value;
            float wf = 0.f;
            if constexpr (e < 4) { if (sl < 10) wf = Wfc[sl*16 + 4*q + e]; }
            afh[e] = (short)(__float_as_uint(wf)>>16);
            afl[e] = (short)(__float_as_uint(wf - hi_part(wf))>>16);
        });
        sfor<0,4>([&](auto R){ constexpr int r = R.value;
            const int gb = 4*q + r;
            biasf[r] = (gb < 10) ? bfc[gb] : 0.f;
        });
        sfor<0,4>([&](auto G){ constexpr int g=G.value;
            bf16x8 Bh = mkB(P1hi[g], Q1hi[g], 0u, 0u);
            bf16x8 Bl = mkB(P1lo[g], Q1lo[g], 0u, 0u);
            f32x4 d = MFMA16(afl, Bh, biasf, 0,0,0);
            d = MFMA16(afh, Bl, d, 0,0,0);
            d = MFMA16(afh, Bh, d, 0,0,0);
            float* orow = out + (s0 + g*16 + sl)*10;
            if (q == 0)      { *(float2*)(orow+0) = float2{d[0],d[1]}; *(float2*)(orow+2) = float2{d[2],d[3]}; }
            else if (q == 1) { *(float2*)(orow+4) = float2{d[0],d[1]}; *(float2*)(orow+6) = float2{d[2],d[3]}; }
            else if (q == 2) { *(float2*)(orow+8) = float2{d[0],d[1]}; }
        });
    }
}

extern "C" void kernel_launch(void* const* d_in, const int* in_sizes, int n_in,
                              void* d_out, int out_size, void* d_ws, size_t ws_size,
                              hipStream_t stream) {
    const float* in   = (const float*)d_in[0];
    const float* Wih0 = (const float*)d_in[1];
    const float* Whh0 = (const float*)d_in[2];
    const float* bih0 = (const float*)d_in[3];
    const float* bhh0 = (const float*)d_in[4];
    const float* Wih1 = (const float*)d_in[5];
    const float* Whh1 = (const float*)d_in[6];
    const float* bih1 = (const float*)d_in[7];
    const float* bhh1 = (const float*)d_in[8];
    const float* Wfc  = (const float*)d_in[9];
    const float* bfc  = (const float*)d_in[10];
    float* out = (float*)d_out;

    int B = in_sizes[0] / 64;           // 262144 samples
    int grid = B / 256;                 // 64 samples/wave * 4 waves/block
    lstm_mfma_kernel<<<grid, 256, 0, stream>>>(in, Wih0, Whh0, bih0, bhh0,
                                               Wih1, Whh1, bih1, bhh1,
                                               Wfc, bfc, out, B);
}

// Round 13
// 81.661 us; speedup vs baseline: 24.0076x; 1.2334x over previous
//
#include <hip/hip_runtime.h>

#define LOG2E 1.44269504088896340736f

typedef short    bf16x8 __attribute__((ext_vector_type(8)));
typedef _Float16 f16x8  __attribute__((ext_vector_type(8)));
typedef float    f32x4  __attribute__((ext_vector_type(4)));

template <int I> struct IntC { static constexpr int value = I; };
template <int I, int N, typename F>
__device__ __forceinline__ void sfor(F&& f) {
    if constexpr (I < N) { f(IntC<I>{}); sfor<I + 1, N>(f); }
}

__device__ __forceinline__ float fexp2(float x){ return __builtin_amdgcn_exp2f(x); }
__device__ __forceinline__ float frcp(float x){ return __builtin_amdgcn_rcpf(x); }

__device__ __forceinline__ float hi_part(float x){
    return __uint_as_float(__float_as_uint(x) & 0xFFFF0000u);
}
// bf16 pack (FC epilogue only)
__device__ __forceinline__ unsigned pk2(float a, float b){
    return __builtin_amdgcn_perm(__float_as_uint(b), __float_as_uint(a), 0x07060302u);
}
__device__ __forceinline__ unsigned pk2lo(float a, float b){
    return pk2(a - hi_part(a), b - hi_part(b));
}
// fp16 RTN pack: 2x v_cvt_f16_f32 (round-nearest) + pack
__device__ __forceinline__ unsigned pkh(float a, float b){
    unsigned short ua = __builtin_bit_cast(unsigned short, (_Float16)a);
    unsigned short ub = __builtin_bit_cast(unsigned short, (_Float16)b);
    return (unsigned)ua | ((unsigned)ub << 16);
}
__device__ __forceinline__ bf16x8 mkB(unsigned d0,unsigned d1,unsigned d2,unsigned d3){
    uint4 u{d0,d1,d2,d3};
    return __builtin_bit_cast(bf16x8, u);
}
__device__ __forceinline__ f16x8 mkBh(unsigned d0,unsigned d1,unsigned d2,unsigned d3){
    uint4 u{d0,d1,d2,d3};
    return __builtin_bit_cast(f16x8, u);
}

#define MFMA16  __builtin_amdgcn_mfma_f32_16x16x32_bf16
#define MFMA16H __builtin_amdgcn_mfma_f32_16x16x32_f16

// LSTM cell tail (unchanged from r12). dd[mt] holds SCALED preacts:
// i',f',o' = -log2e*pre, g' = 2log2e*pre (scales folded into weights+biases).
// sigma = 1/(1+exp2(-L*pre)); tanh = (E-1)/(E+1). rcp pair/quad-batched.
__device__ __forceinline__ f32x4 cell_tail(const f32x4 (&dd)[4], f32x4& c){
    f32x4 Ei, Ef, Eg, Eo;
    sfor<0,4>([&](auto R){ constexpr int r=R.value;
        Ei[r] = fexp2(dd[0][r]);
        Ef[r] = fexp2(dd[1][r]);
        Eg[r] = fexp2(dd[2][r]);
        Eo[r] = fexp2(dd[3][r]);
    });
    f32x4 ov, cn;
    sfor<0,4>([&](auto R){ constexpr int r=R.value;
        float Ai = 1.f + Ei[r], Af = 1.f + Ef[r];
        float Ag = 1.f + Eg[r], Ao = 1.f + Eo[r];
        float p  = Ai*Af;  float rp = frcp(p);
        float iv = Af*rp;                 // sigma(i)
        float fv = Ai*rp;                 // sigma(f)
        float q2 = Ag*Ao;  float rq = frcp(q2);
        float gr = Ao*rq;                 // 1/Ag
        ov[r]    = Ag*rq;                 // sigma(o)
        float gv = (Eg[r]-1.f)*gr;        // tanh(g)
        cn[r] = fv*c[r] + iv*gv;
    });
    c = cn;
    f32x4 tc;
    sfor<0,4>([&](auto R){ constexpr int r=R.value;
        tc[r] = fexp2(cn[r]*(2.f*LOG2E));
    });
    float B0=tc[0]+1.f, B1=tc[1]+1.f, B2=tc[2]+1.f, B3=tc[3]+1.f;
    float P2=B0*B1, P3=P2*B2, P4=P3*B3;
    float r4=frcp(P4);
    float R3=P3*r4;
    float r3=B3*r4;
    float R2=P2*r3;
    float r2=B2*r3;
    float R1=B0*r2;
    float R0=B1*r2;
    f32x4 hv;
    hv[0] = ov[0]*((tc[0]-1.f)*R0);
    hv[1] = ov[1]*((tc[1]-1.f)*R1);
    hv[2] = ov[2]*((tc[2]-1.f)*R2);
    hv[3] = ov[3]*((tc[3]-1.f)*R3);
    return hv;
}

// One wave = 64 samples (4 groups of 16), ZERO LDS. Virtual-K permutation:
// lane (q,sl) owns C/D rows 4q..4q+3 of sample sl; B element k=8q+e is that
// lane's own packed registers. SINGLE fp16 MFMA per gate tile (RTN converts:
// rel err 2^-11/elem; true output err ~2e-3 vs 6.13e-3 threshold with the
// ref itself bf16-quantized at 2^-9). FC epilogue stays bf16 hi/lo 3-MFMA
// fed from f32 last-h (undamped path to output).
//   layer0 K: e<4 -> h0[4q+e]; e==4,5 -> x[2q],x[2q+1]; e>=6 -> 0
//   layer1 K: e<4 -> h0[4q+e]; e>=4 -> h1[4q+e-4]
//   FC     K: e<4 -> h1[4q+e]; e>=4 -> 0
__global__
__attribute__((amdgpu_flat_work_group_size(256,256)))
__attribute__((amdgpu_waves_per_eu(1,8)))
void lstm_mfma_kernel(const float* __restrict__ in,
                      const float* __restrict__ Wih0, const float* __restrict__ Whh0,
                      const float* __restrict__ bih0, const float* __restrict__ bhh0,
                      const float* __restrict__ Wih1, const float* __restrict__ Whh1,
                      const float* __restrict__ bih1, const float* __restrict__ bhh1,
                      const float* __restrict__ Wfc,  const float* __restrict__ bfc,
                      float* __restrict__ out, int B)
{
    const int lane = threadIdx.x & 63;
    const int wid  = threadIdx.x >> 6;
    const int q  = lane >> 4;       // k-group / row-group
    const int sl = lane & 15;       // sample slot (MFMA col)
    const long s0 = (long)(blockIdx.x*4 + wid)*64;

    // ---- weight A-frags (fp16 RTN, VGPR-resident), virtual-K layout,
    //      exp-scale folded per gate: mt==2 (g): +2*log2e, else -log2e ----
    f16x8 a0[4], a1[4];
    f32x4 bias0[4], bias1[4];
    sfor<0,4>([&](auto MT){ constexpr int mt = MT.value;
        constexpr float SC = (mt==2) ? (2.f*LOG2E) : (-LOG2E);
        const int gr = 16*mt + sl;                 // gate row (A row = sl)
        sfor<0,8>([&](auto E){ constexpr int e = E.value;
            float w0;
            if constexpr (e < 4)      w0 = Whh0[gr*16 + 4*q + e];
            else if constexpr (e < 6) w0 = Wih0[gr*8 + 2*q + (e-4)];
            else                      w0 = 0.f;
            a0[mt][e] = (_Float16)(w0 * SC);
            float w1;
            if constexpr (e < 4) w1 = Wih1[gr*16 + 4*q + e];
            else                 w1 = Whh1[gr*16 + 4*q + (e-4)];
            a1[mt][e] = (_Float16)(w1 * SC);
        });
        sfor<0,4>([&](auto R){ constexpr int r = R.value;
            const int gb = 16*mt + 4*q + r;        // C/D row = 4q+r
            bias0[mt][r] = (bih0[gb] + bhh0[gb]) * SC;
            bias1[mt][r] = (bih1[gb] + bhh1[gb]) * SC;
        });
    });

    // ---- state x4 groups: fp16-packed h + f32 cell, all lane-local ----
    unsigned P0h[4]={0,0,0,0}, Q0h[4]={0,0,0,0};
    unsigned P1h[4]={0,0,0,0}, Q1h[4]={0,0,0,0};
    f32x4 c0[4], c1[4], hl1[4];
    sfor<0,4>([&](auto G){ constexpr int g=G.value;
        c0[g] = f32x4{0,0,0,0}; c1[g] = f32x4{0,0,0,0};
        hl1[g] = f32x4{0,0,0,0};
    });

    // ---- x stream: EVERY lane loads float2 = x_t[sample][2q..2q+1] ----
    const float* xbase = in + (s0 + sl)*64 + 2*q;
    float2 xv[4];
    sfor<0,4>([&](auto G){ constexpr int g=G.value;
        xv[g] = *(const float2*)(xbase + g*1024);
    });

#pragma unroll 2
    for (int t = 0; t < 8; ++t) {
        // prefetch next step's x (t==7: reload t=0, discarded — in bounds)
        const int nxt = (t==7) ? 0 : (t+1)*8;
        float2 xn[4];
        sfor<0,4>([&](auto G){ constexpr int g=G.value;
            xn[g] = *(const float2*)(xbase + g*1024 + nxt);
        });

        // ================= layer 0 (4 groups: independent chains) ==========
        sfor<0,4>([&](auto G){ constexpr int g=G.value;
            const unsigned xh = pkh(xv[g].x, xv[g].y);
            f16x8 Bh = mkBh(P0h[g], Q0h[g], xh, 0u);
            f32x4 dd[4];
            sfor<0,4>([&](auto MT){ constexpr int mt = MT.value;
                dd[mt] = MFMA16H(a0[mt], Bh, bias0[mt], 0,0,0);
            });
            f32x4 hv = cell_tail(dd, c0[g]);
            P0h[g] = pkh(hv[0],hv[1]);  Q0h[g] = pkh(hv[2],hv[3]);
        });

        // ================= layer 1 (4 groups) ==============================
        sfor<0,4>([&](auto G){ constexpr int g=G.value;
            f16x8 Bh = mkBh(P0h[g], Q0h[g], P1h[g], Q1h[g]);
            f32x4 dd[4];
            sfor<0,4>([&](auto MT){ constexpr int mt = MT.value;
                dd[mt] = MFMA16H(a1[mt], Bh, bias1[mt], 0,0,0);
            });
            f32x4 hv = cell_tail(dd, c1[g]);
            hl1[g] = hv;                           // f32 last-h for FC
            P1h[g] = pkh(hv[0],hv[1]);  Q1h[g] = pkh(hv[2],hv[3]);
        });

        sfor<0,4>([&](auto G){ constexpr int g=G.value; xv[g] = xn[g]; });
    }

    // ================= FC (bf16 hi/lo 3-MFMA, f32 last-h, UNSCALED) ========
    {
        bf16x8 afh, afl;
        f32x4 biasf;
        sfor<0,8>([&](auto E){ constexpr int e = E.value;
            float wf = 0.f;
            if constexpr (e < 4) { if (sl < 10) wf = Wfc[sl*16 + 4*q + e]; }
            afh[e] = (short)(__float_as_uint(wf)>>16);
            afl[e] = (short)(__float_as_uint(wf - hi_part(wf))>>16);
        });
        sfor<0,4>([&](auto R){ constexpr int r = R.value;
            const int gb = 4*q + r;
            biasf[r] = (gb < 10) ? bfc[gb] : 0.f;
        });
        sfor<0,4>([&](auto G){ constexpr int g=G.value;
            const unsigned Fh0 = pk2(hl1[g][0], hl1[g][1]);
            const unsigned Fh1 = pk2(hl1[g][2], hl1[g][3]);
            const unsigned Fl0 = pk2lo(hl1[g][0], hl1[g][1]);
            const unsigned Fl1 = pk2lo(hl1[g][2], hl1[g][3]);
            bf16x8 Bh = mkB(Fh0, Fh1, 0u, 0u);
            bf16x8 Bl = mkB(Fl0, Fl1, 0u, 0u);
            f32x4 d = MFMA16(afl, Bh, biasf, 0,0,0);
            d = MFMA16(afh, Bl, d, 0,0,0);
            d = MFMA16(afh, Bh, d, 0,0,0);
            float* orow = out + (s0 + g*16 + sl)*10;
            if (q == 0)      { *(float2*)(orow+0) = float2{d[0],d[1]}; *(float2*)(orow+2) = float2{d[2],d[3]}; }
            else if (q == 1) { *(float2*)(orow+4) = float2{d[0],d[1]}; *(float2*)(orow+6) = float2{d[2],d[3]}; }
            else if (q == 2) { *(float2*)(orow+8) = float2{d[0],d[1]}; }
        });
    }
}

extern "C" void kernel_launch(void* const* d_in, const int* in_sizes, int n_in,
                              void* d_out, int out_size, void* d_ws, size_t ws_size,
                              hipStream_t stream) {
    const float* in   = (const float*)d_in[0];
    const float* Wih0 = (const float*)d_in[1];
    const float* Whh0 = (const float*)d_in[2];
    const float* bih0 = (const float*)d_in[3];
    const float* bhh0 = (const float*)d_in[4];
    const float* Wih1 = (const float*)d_in[5];
    const float* Whh1 = (const float*)d_in[6];
    const float* bih1 = (const float*)d_in[7];
    const float* bhh1 = (const float*)d_in[8];
    const float* Wfc  = (const float*)d_in[9];
    const float* bfc  = (const float*)d_in[10];
    float* out = (float*)d_out;

    int B = in_sizes[0] / 64;           // 262144 samples
    int grid = B / 256;                 // 64 samples/wave * 4 waves/block
    lstm_mfma_kernel<<<grid, 256, 0, stream>>>(in, Wih0, Whh0, bih0, bhh0,
                                               Wih1, Whh1, bih1, bhh1,
                                               Wfc, bfc, out, B);
}